// Round 2
// baseline (712.376 us; speedup 1.0000x reference)
//
#include <hip/hip_runtime.h>
#include <cstdint>
#include <cstddef>

#define DEVFN static __device__ __forceinline__

typedef __attribute__((ext_vector_type(4))) float f32x4;
typedef __attribute__((ext_vector_type(8))) __bf16 bf16x8;

typedef __attribute__((address_space(1))) void gvoid;
typedef __attribute__((address_space(3))) void svoid;

DEVFN unsigned short f32_to_bf16_bits(float f) {
  uint32_t u = __builtin_bit_cast(uint32_t, f);
  return (unsigned short)((u + 0x7fffu + ((u >> 16) & 1u)) >> 16);
}
DEVFN float bf16_lo(uint32_t d) {  // low 16 bits -> float
  return __builtin_bit_cast(float, d << 16);
}
DEVFN float bf16_hi(uint32_t d) {  // high 16 bits -> float
  return __builtin_bit_cast(float, d & 0xffff0000u);
}
DEVFN uint32_t pack_bf16x2(float lo, float hi) {
  return (uint32_t)f32_to_bf16_bits(lo) | ((uint32_t)f32_to_bf16_bits(hi) << 16);
}

// global -> LDS direct copy, 16B per lane. LDS base must be wave-uniform.
DEVFN void load_lds16(const unsigned short* g, unsigned short* l) {
  __builtin_amdgcn_global_load_lds((gvoid*)g, (svoid*)l, 16, 0, 0);
}

// ---------------- all fp32 -> bf16 conversions in ONE launch ----------------
// chunk = 8 elems. qb: 524288 chunks, Wq/Wv/Wo: 32768 each, W1/W2: 65536 each.
__global__ __launch_bounds__(256) void cvt_all(
    const float* __restrict__ q, const float* __restrict__ Wq,
    const float* __restrict__ Wv, const float* __restrict__ Wo,
    const float* __restrict__ W1, const float* __restrict__ W2,
    unsigned short* __restrict__ qb, unsigned short* __restrict__ Wqb,
    unsigned short* __restrict__ Wvb, unsigned short* __restrict__ Wob,
    unsigned short* __restrict__ W1b, unsigned short* __restrict__ W2b) {
  int i = (int)(blockIdx.x * 256 + threadIdx.x);
  const float* src;
  unsigned short* dst;
  int off;
  if (i < 524288)      { src = q;  dst = qb;  off = i; }
  else if (i < 557056) { src = Wq; dst = Wqb; off = i - 524288; }
  else if (i < 589824) { src = Wv; dst = Wvb; off = i - 557056; }
  else if (i < 622592) { src = Wo; dst = Wob; off = i - 589824; }
  else if (i < 688128) { src = W1; dst = W1b; off = i - 622592; }
  else                 { src = W2; dst = W2b; off = i - 688128; }
  const float4* p = (const float4*)src;
  float4 a = p[2 * off], b = p[2 * off + 1];
  union { unsigned short s[8]; uint4 v; } o;
  o.s[0] = f32_to_bf16_bits(a.x); o.s[1] = f32_to_bf16_bits(a.y);
  o.s[2] = f32_to_bf16_bits(a.z); o.s[3] = f32_to_bf16_bits(a.w);
  o.s[4] = f32_to_bf16_bits(b.x); o.s[5] = f32_to_bf16_bits(b.y);
  o.s[6] = f32_to_bf16_bits(b.z); o.s[7] = f32_to_bf16_bits(b.w);
  ((uint4*)dst)[off] = o.v;
}

// WkT[h][j][d] = Wk[h*64+d][j]   (8*512*64 = 262144 elems)
__global__ __launch_bounds__(256) void wkt_kernel(const float* __restrict__ Wk,
                                                  unsigned short* __restrict__ WkT) {
  int idx = (int)(blockIdx.x * 256 + threadIdx.x);
  int d = idx & 63;
  int j = (idx >> 6) & 511;
  int h = idx >> 15;
  WkT[idx] = f32_to_bf16_bits(Wk[((h << 6) + d) * 512 + j]);
}

// ---------------- bf16 MFMA GEMM, B given transposed (Bt[n][k]) ----------------
template<int BN, bool OUT_BF16, bool RELU, bool ADD_RES>
__global__ __launch_bounds__(256)
void gemm_bt(const unsigned short* __restrict__ A, int lda, long long zA,
             const unsigned short* __restrict__ Bt, int ldb, long long zB,
             void* __restrict__ Cv, int ldc, long long zC,
             const float* __restrict__ bias, int zBias,
             const float* __restrict__ res, int ldres,
             int K) {
  constexpr int BM = 128;
  constexpr int WN = BN / 2;   // 64 or 32
  constexpr int NT = WN / 16;  // 4 or 2
  __shared__ __align__(16) unsigned short As[BM * 32];
  __shared__ __align__(16) unsigned short Bs[BN * 32];

  const int tid = (int)threadIdx.x;
  const int lane = tid & 63;
  const int w = tid >> 6;
  const int wm = w >> 1;
  const int wn = w & 1;
  const int m0 = (int)blockIdx.y * BM;
  const int n0 = (int)blockIdx.x * BN;
  const long long z = (long long)blockIdx.z;

  A += z * zA;
  Bt += z * zB;
  const float* biasz = bias ? (bias + z * zBias) : nullptr;

  f32x4 acc[4][NT];
#pragma unroll
  for (int i = 0; i < 4; ++i)
#pragma unroll
    for (int j = 0; j < NT; ++j) acc[i][j] = f32x4{0.f, 0.f, 0.f, 0.f};

  const int o0 = w * 1024 + lane * 16;
  const int r0 = o0 >> 6, c0 = (o0 & 63) >> 1;
  const int o1 = o0 + 4096;
  const int r1 = o1 >> 6, c1 = (o1 & 63) >> 1;

  const int kIters = K / 32;
  for (int kt = 0; kt < kIters; ++kt) {
    const int k0 = kt * 32;
    __syncthreads();
    load_lds16(A + (size_t)(m0 + r0) * lda + (k0 + c0), As + w * 512);
    load_lds16(A + (size_t)(m0 + r1) * lda + (k0 + c1), As + 2048 + w * 512);
    if (BN == 128) {
      load_lds16(Bt + (size_t)(n0 + r0) * ldb + (k0 + c0), Bs + w * 512);
      load_lds16(Bt + (size_t)(n0 + r1) * ldb + (k0 + c1), Bs + 2048 + w * 512);
    } else {
      load_lds16(Bt + (size_t)(n0 + r0) * ldb + (k0 + c0), Bs + w * 512);
    }
    asm volatile("s_waitcnt vmcnt(0)" ::: "memory");
    __syncthreads();

    const int fr = lane & 15;
    const int kq = lane >> 4;
    bf16x8 af[4], bf[NT];
#pragma unroll
    for (int i = 0; i < 4; ++i) {
      const int m = wm * 64 + i * 16 + fr;
      af[i] = __builtin_bit_cast(bf16x8, *(const uint4*)(As + m * 32 + kq * 8));
    }
#pragma unroll
    for (int j = 0; j < NT; ++j) {
      const int n = wn * WN + j * 16 + fr;
      bf[j] = __builtin_bit_cast(bf16x8, *(const uint4*)(Bs + n * 32 + kq * 8));
    }
#pragma unroll
    for (int i = 0; i < 4; ++i)
#pragma unroll
      for (int j = 0; j < NT; ++j)
        acc[i][j] = __builtin_amdgcn_mfma_f32_16x16x32_bf16(af[i], bf[j], acc[i][j], 0, 0, 0);
  }

  const int fr = lane & 15;
  const int rq = lane >> 4;
  unsigned short* Cb = (unsigned short*)Cv + z * zC;
  float* Cf = (float*)Cv + z * zC;
#pragma unroll
  for (int i = 0; i < 4; ++i) {
    const int rbase = m0 + wm * 64 + i * 16 + rq * 4;
#pragma unroll
    for (int j = 0; j < NT; ++j) {
      const int col = n0 + wn * WN + j * 16 + fr;
      const float bvv = biasz ? biasz[col] : 0.f;
#pragma unroll
      for (int r = 0; r < 4; ++r) {
        float v = acc[i][j][r] + bvv;
        if (ADD_RES) v += res[(size_t)(rbase + r) * ldres + col];
        if (RELU) v = fmaxf(v, 0.f);
        if (OUT_BF16) Cb[(size_t)(rbase + r) * ldc + col] = f32_to_bf16_bits(v);
        else Cf[(size_t)(rbase + r) * ldc + col] = v;
      }
    }
  }
}

// ---------------- fused scores/softmax/vbar (in-place U -> vbar), v2 ----------------
// Streaming: 8 tokens per block, double-buffered bf16 LDS k/v, packed dword reads.
// s[h,c] = U[n,h,:] . key[n*8+c,:] / 8; softmax over c;
// vbar[n,h,:] = sum_c att[c] * value[n*8+c,:]  (written over U, bf16)
__global__ __launch_bounds__(256, 4) void attn_kernel(const float* __restrict__ key,
                                                      const float* __restrict__ value,
                                                      unsigned short* __restrict__ U) {
  __shared__ uint2 kb[2][1024];  // 8 KB per buffer (8 rows x 512 cols bf16)
  __shared__ uint2 vb[2][1024];
  const int tid = (int)threadIdx.x;
  const int lane = tid & 63;
  const int w = tid >> 6;
  const int n0 = (int)blockIdx.x * 8;

  float4 kr[4], vr[4];

  auto issue = [&](int n) {
    const float4* kg = (const float4*)(key + (size_t)n * 4096);
    const float4* vg = (const float4*)(value + (size_t)n * 4096);
#pragma unroll
    for (int j = 0; j < 4; ++j) {
      kr[j] = kg[tid + 256 * j];
      vr[j] = vg[tid + 256 * j];
    }
  };
  auto commit = [&](int buf) {
#pragma unroll
    for (int j = 0; j < 4; ++j) {
      uint2 kp, vp;
      kp.x = pack_bf16x2(kr[j].x, kr[j].y);
      kp.y = pack_bf16x2(kr[j].z, kr[j].w);
      vp.x = pack_bf16x2(vr[j].x, vr[j].y);
      vp.y = pack_bf16x2(vr[j].z, vr[j].w);
      kb[buf][tid + 256 * j] = kp;
      vb[buf][tid + 256 * j] = vp;
    }
  };

  issue(n0);
  commit(0);
  __syncthreads();

  for (int i = 0; i < 8; ++i) {
    const int n = n0 + i;
    if (i < 7) issue(n + 1);

    const uint32_t* k32 = (const uint32_t*)kb[i & 1];
    const uint32_t* v32 = (const uint32_t*)vb[i & 1];
    uint32_t* Un32 = (uint32_t*)(U + (size_t)n * 4096);

#pragma unroll
    for (int hh = 0; hh < 2; ++hh) {
      const int h = w * 2 + hh;
      float ulo[4], uhi[4];
#pragma unroll
      for (int t = 0; t < 4; ++t) {
        uint32_t d = Un32[h * 256 + lane + 64 * t];
        ulo[t] = bf16_lo(d);
        uhi[t] = bf16_hi(d);
      }
      float zc[8];
      float zmax = -1e30f;
#pragma unroll
      for (int c = 0; c < 8; ++c) {
        float p = 0.f;
#pragma unroll
        for (int t = 0; t < 4; ++t) {
          uint32_t kd = k32[c * 256 + lane + 64 * t];
          p += ulo[t] * bf16_lo(kd) + uhi[t] * bf16_hi(kd);
        }
#pragma unroll
        for (int off = 32; off > 0; off >>= 1) p += __shfl_xor(p, off, 64);
        zc[c] = p * 0.125f;  // / sqrt(64)
        zmax = fmaxf(zmax, zc[c]);
      }
      float se = 0.f;
#pragma unroll
      for (int c = 0; c < 8; ++c) { zc[c] = __expf(zc[c] - zmax); se += zc[c]; }
      const float inv = 1.f / se;
#pragma unroll
      for (int c = 0; c < 8; ++c) zc[c] *= inv;
#pragma unroll
      for (int t = 0; t < 4; ++t) {
        const int p = lane + 64 * t;
        float alo = 0.f, ahi = 0.f;
#pragma unroll
        for (int c = 0; c < 8; ++c) {
          uint32_t vd = v32[c * 256 + p];
          alo += zc[c] * bf16_lo(vd);
          ahi += zc[c] * bf16_hi(vd);
        }
        Un32[h * 256 + p] = pack_bf16x2(alo, ahi);
      }
    }

    if (i < 7) commit((i + 1) & 1);
    __syncthreads();
  }
}

// ---------------- LayerNorm over rows of 512; wave per row ----------------
__global__ __launch_bounds__(256) void ln_kernel(const float* __restrict__ in,
                                                 const float* __restrict__ g,
                                                 const float* __restrict__ b,
                                                 float* __restrict__ outf,
                                                 unsigned short* __restrict__ outb) {
  const int lane = (int)threadIdx.x & 63;
  const size_t row = (size_t)blockIdx.x * 4 + (threadIdx.x >> 6);
  const int col = lane * 8;
  const float* x = in + row * 512;
  float4 a0 = *(const float4*)(x + col);
  float4 a1 = *(const float4*)(x + col + 4);
  float v[8] = {a0.x, a0.y, a0.z, a0.w, a1.x, a1.y, a1.z, a1.w};
  float s = 0.f, sq = 0.f;
#pragma unroll
  for (int t = 0; t < 8; ++t) { s += v[t]; sq += v[t] * v[t]; }
#pragma unroll
  for (int off = 32; off > 0; off >>= 1) {
    s += __shfl_xor(s, off, 64);
    sq += __shfl_xor(sq, off, 64);
  }
  const float mean = s * (1.f / 512.f);
  const float var = sq * (1.f / 512.f) - mean * mean;
  const float rstd = rsqrtf(var + 1e-5f);
  float o[8];
#pragma unroll
  for (int t = 0; t < 8; ++t) o[t] = (v[t] - mean) * rstd * g[col + t] + b[col + t];
  if (outf) {
    *(float4*)(outf + row * 512 + col) = make_float4(o[0], o[1], o[2], o[3]);
    *(float4*)(outf + row * 512 + col + 4) = make_float4(o[4], o[5], o[6], o[7]);
  }
  if (outb) {
    union { unsigned short s_[8]; uint4 v_; } u;
#pragma unroll
    for (int t = 0; t < 8; ++t) u.s_[t] = f32_to_bf16_bits(o[t]);
    *(uint4*)(outb + row * 512 + col) = u.v_;
  }
}

extern "C" void kernel_launch(void* const* d_in, const int* in_sizes, int n_in,
                              void* d_out, int out_size, void* d_ws, size_t ws_size,
                              hipStream_t stream) {
  const float* query = (const float*)d_in[0];
  const float* key   = (const float*)d_in[1];
  const float* value = (const float*)d_in[2];
  const float* Wq = (const float*)d_in[3];
  const float* bq = (const float*)d_in[4];
  const float* Wk = (const float*)d_in[5];
  // bk (d_in[6]) cancels exactly in the softmax -> unused
  const float* Wv = (const float*)d_in[7];
  const float* bv = (const float*)d_in[8];
  const float* Wo = (const float*)d_in[9];
  const float* bo = (const float*)d_in[10];
  const float* ln1g = (const float*)d_in[11];
  const float* ln1b = (const float*)d_in[12];
  const float* W1 = (const float*)d_in[13];
  const float* b1 = (const float*)d_in[14];
  const float* W2 = (const float*)d_in[15];
  const float* b2 = (const float*)d_in[16];
  const float* ln2g = (const float*)d_in[17];
  const float* ln2b = (const float*)d_in[18];
  float* out = (float*)d_out;

  char* ws = (char*)d_ws;
  size_t off = 0;
  auto alloc = [&](size_t bytes) -> void* {
    off = (off + 255) & ~(size_t)255;
    void* p = ws + off;
    off += bytes;
    return p;
  };

  const int N = 8192;  // tokens = F*B
  unsigned short* qb   = (unsigned short*)alloc((size_t)N * 512 * 2);
  unsigned short* Wqb  = (unsigned short*)alloc(512 * 512 * 2);
  unsigned short* Wvb  = (unsigned short*)alloc(512 * 512 * 2);
  unsigned short* Wob  = (unsigned short*)alloc(512 * 512 * 2);
  unsigned short* W1b  = (unsigned short*)alloc(1024 * 512 * 2);
  unsigned short* W2b  = (unsigned short*)alloc(512 * 1024 * 2);
  unsigned short* WkT  = (unsigned short*)alloc(8 * 512 * 64 * 2);
  unsigned short* Qp   = (unsigned short*)alloc((size_t)N * 512 * 2);   // later reused as x
  unsigned short* U    = (unsigned short*)alloc((size_t)N * 4096 * 2);  // U, then vbar in-place
  float*          h1pre= (float*)alloc((size_t)N * 512 * 4);            // later reused as o2pre
  unsigned short* h1b  = (unsigned short*)alloc((size_t)N * 512 * 2);
  float*          h1f  = (float*)alloc((size_t)N * 512 * 4);
  unsigned short* mid  = (unsigned short*)alloc((size_t)N * 1024 * 2);
  unsigned short* x    = Qp;       // reuse (Qp dead after U-GEMM)
  float*          o2pre= h1pre;    // reuse (raw pre-LN1 dead after LN1)
  (void)ws_size; (void)in_sizes; (void)n_in; (void)out_size;

  dim3 blk(256);
  // all straight conversions in one launch; WkT transpose separately
  cvt_all<<<2944, blk, 0, stream>>>(query, Wq, Wv, Wo, W1, W2,
                                    qb, Wqb, Wvb, Wob, W1b, W2b);
  wkt_kernel<<<1024, blk, 0, stream>>>(Wk, WkT);

  // Qp = qb @ Wq^T + bq            [8192 x 512], bf16
  gemm_bt<128, true, false, false><<<dim3(4, 64, 1), blk, 0, stream>>>(
      qb, 512, 0, Wqb, 512, 0, Qp, 512, 0, bq, 0, nullptr, 0, 512);
  // U[n, h*512+j] = Qp[n, h*64:..] @ WkT[h]   (K=64 per head, grid.z = head)
  gemm_bt<128, true, false, false><<<dim3(4, 64, 8), blk, 0, stream>>>(
      Qp, 512, 64, WkT, 64, 32768, U, 4096, 512, nullptr, 0, nullptr, 0, 64);
  // scores + softmax + vbar (in place over U); 8 tokens/block, double-buffered
  attn_kernel<<<1024, blk, 0, stream>>>(key, value, U);
  // x[n, h*64+d] = vbar[n,h,:] @ Wv_head^T + bv_head   (N=64 per head)
  gemm_bt<64, true, false, false><<<dim3(1, 64, 8), blk, 0, stream>>>(
      U, 4096, 512, Wvb, 512, 32768, x, 512, 64, bv, 64, nullptr, 0, 512);
  // h1pre = x @ Wo^T + bo + query   (fp32)
  gemm_bt<128, false, false, true><<<dim3(4, 64, 1), blk, 0, stream>>>(
      x, 512, 0, Wob, 512, 0, h1pre, 512, 0, bo, 0, query, 512, 512);
  // h1 = LN(h1pre) -> h1f (fp32 residual) + h1b (bf16 GEMM input)
  ln_kernel<<<2048, blk, 0, stream>>>(h1pre, ln1g, ln1b, h1f, h1b);
  // mid = relu(h1 @ W1^T + b1)      [8192 x 1024], bf16
  gemm_bt<128, true, true, false><<<dim3(8, 64, 1), blk, 0, stream>>>(
      h1b, 512, 0, W1b, 512, 0, mid, 1024, 0, b1, 0, nullptr, 0, 512);
  // o2pre = mid @ W2^T + b2 + h1    (fp32)
  gemm_bt<128, false, false, true><<<dim3(4, 64, 1), blk, 0, stream>>>(
      mid, 1024, 0, W2b, 1024, 0, o2pre, 512, 0, b2, 0, h1f, 512, 1024);
  // out = LN(o2pre)
  ln_kernel<<<2048, blk, 0, stream>>>(o2pre, ln2g, ln2b, out, nullptr);
}

// Round 3
// 560.191 us; speedup vs baseline: 1.2717x; 1.2717x over previous
//
#include <hip/hip_runtime.h>
#include <cstdint>
#include <cstddef>

#define DEVFN static __device__ __forceinline__

typedef __attribute__((ext_vector_type(4))) float f32x4;
typedef __attribute__((ext_vector_type(8))) __bf16 bf16x8;

typedef __attribute__((address_space(1))) void gvoid;
typedef __attribute__((address_space(3))) void svoid;

DEVFN unsigned short f32_to_bf16_bits(float f) {
  uint32_t u = __builtin_bit_cast(uint32_t, f);
  return (unsigned short)((u + 0x7fffu + ((u >> 16) & 1u)) >> 16);
}
DEVFN float bf16_lo(uint32_t d) {  // low 16 bits -> float
  return __builtin_bit_cast(float, d << 16);
}
DEVFN float bf16_hi(uint32_t d) {  // high 16 bits -> float
  return __builtin_bit_cast(float, d & 0xffff0000u);
}
DEVFN uint32_t pack_bf16x2(float lo, float hi) {
  return (uint32_t)f32_to_bf16_bits(lo) | ((uint32_t)f32_to_bf16_bits(hi) << 16);
}

// global -> LDS direct copy, 16B per lane. LDS base must be wave-uniform;
// lane i lands at lds + i*16 bytes.
DEVFN void load_lds16(const void* g, void* l) {
  __builtin_amdgcn_global_load_lds((const gvoid*)g, (svoid*)l, 16, 0, 0);
}

// ---------------- all fp32 -> bf16 conversions in ONE launch ----------------
// chunk = 8 elems. qb: 524288 chunks, Wq/Wv/Wo: 32768 each, W1/W2: 65536 each.
__global__ __launch_bounds__(256) void cvt_all(
    const float* __restrict__ q, const float* __restrict__ Wq,
    const float* __restrict__ Wv, const float* __restrict__ Wo,
    const float* __restrict__ W1, const float* __restrict__ W2,
    unsigned short* __restrict__ qb, unsigned short* __restrict__ Wqb,
    unsigned short* __restrict__ Wvb, unsigned short* __restrict__ Wob,
    unsigned short* __restrict__ W1b, unsigned short* __restrict__ W2b) {
  int i = (int)(blockIdx.x * 256 + threadIdx.x);
  const float* src;
  unsigned short* dst;
  int off;
  if (i < 524288)      { src = q;  dst = qb;  off = i; }
  else if (i < 557056) { src = Wq; dst = Wqb; off = i - 524288; }
  else if (i < 589824) { src = Wv; dst = Wvb; off = i - 557056; }
  else if (i < 622592) { src = Wo; dst = Wob; off = i - 589824; }
  else if (i < 688128) { src = W1; dst = W1b; off = i - 622592; }
  else                 { src = W2; dst = W2b; off = i - 688128; }
  const float4* p = (const float4*)src;
  float4 a = p[2 * off], b = p[2 * off + 1];
  union { unsigned short s[8]; uint4 v; } o;
  o.s[0] = f32_to_bf16_bits(a.x); o.s[1] = f32_to_bf16_bits(a.y);
  o.s[2] = f32_to_bf16_bits(a.z); o.s[3] = f32_to_bf16_bits(a.w);
  o.s[4] = f32_to_bf16_bits(b.x); o.s[5] = f32_to_bf16_bits(b.y);
  o.s[6] = f32_to_bf16_bits(b.z); o.s[7] = f32_to_bf16_bits(b.w);
  ((uint4*)dst)[off] = o.v;
}

// WkT[h][j][d] = Wk[h*64+d][j]   (8*512*64 = 262144 elems)
__global__ __launch_bounds__(256) void wkt_kernel(const float* __restrict__ Wk,
                                                  unsigned short* __restrict__ WkT) {
  int idx = (int)(blockIdx.x * 256 + threadIdx.x);
  int d = idx & 63;
  int j = (idx >> 6) & 511;
  int h = idx >> 15;
  WkT[idx] = f32_to_bf16_bits(Wk[((h << 6) + d) * 512 + j]);
}

// ---------------- bf16 MFMA GEMM, B given transposed (Bt[n][k]) ----------------
template<int BN, bool OUT_BF16, bool RELU, bool ADD_RES>
__global__ __launch_bounds__(256)
void gemm_bt(const unsigned short* __restrict__ A, int lda, long long zA,
             const unsigned short* __restrict__ Bt, int ldb, long long zB,
             void* __restrict__ Cv, int ldc, long long zC,
             const float* __restrict__ bias, int zBias,
             const float* __restrict__ res, int ldres,
             int K) {
  constexpr int BM = 128;
  constexpr int WN = BN / 2;   // 64 or 32
  constexpr int NT = WN / 16;  // 4 or 2
  __shared__ __align__(16) unsigned short As[BM * 32];
  __shared__ __align__(16) unsigned short Bs[BN * 32];

  const int tid = (int)threadIdx.x;
  const int lane = tid & 63;
  const int w = tid >> 6;
  const int wm = w >> 1;
  const int wn = w & 1;
  const int m0 = (int)blockIdx.y * BM;
  const int n0 = (int)blockIdx.x * BN;
  const long long z = (long long)blockIdx.z;

  A += z * zA;
  Bt += z * zB;
  const float* biasz = bias ? (bias + z * zBias) : nullptr;

  f32x4 acc[4][NT];
#pragma unroll
  for (int i = 0; i < 4; ++i)
#pragma unroll
    for (int j = 0; j < NT; ++j) acc[i][j] = f32x4{0.f, 0.f, 0.f, 0.f};

  const int o0 = w * 1024 + lane * 16;
  const int r0 = o0 >> 6, c0 = (o0 & 63) >> 1;
  const int o1 = o0 + 4096;
  const int r1 = o1 >> 6, c1 = (o1 & 63) >> 1;

  const int kIters = K / 32;
  for (int kt = 0; kt < kIters; ++kt) {
    const int k0 = kt * 32;
    __syncthreads();
    load_lds16(A + (size_t)(m0 + r0) * lda + (k0 + c0), As + w * 512);
    load_lds16(A + (size_t)(m0 + r1) * lda + (k0 + c1), As + 2048 + w * 512);
    if (BN == 128) {
      load_lds16(Bt + (size_t)(n0 + r0) * ldb + (k0 + c0), Bs + w * 512);
      load_lds16(Bt + (size_t)(n0 + r1) * ldb + (k0 + c1), Bs + 2048 + w * 512);
    } else {
      load_lds16(Bt + (size_t)(n0 + r0) * ldb + (k0 + c0), Bs + w * 512);
    }
    asm volatile("s_waitcnt vmcnt(0)" ::: "memory");
    __syncthreads();

    const int fr = lane & 15;
    const int kq = lane >> 4;
    bf16x8 af[4], bf[NT];
#pragma unroll
    for (int i = 0; i < 4; ++i) {
      const int m = wm * 64 + i * 16 + fr;
      af[i] = __builtin_bit_cast(bf16x8, *(const uint4*)(As + m * 32 + kq * 8));
    }
#pragma unroll
    for (int j = 0; j < NT; ++j) {
      const int n = wn * WN + j * 16 + fr;
      bf[j] = __builtin_bit_cast(bf16x8, *(const uint4*)(Bs + n * 32 + kq * 8));
    }
#pragma unroll
    for (int i = 0; i < 4; ++i)
#pragma unroll
      for (int j = 0; j < NT; ++j)
        acc[i][j] = __builtin_amdgcn_mfma_f32_16x16x32_bf16(af[i], bf[j], acc[i][j], 0, 0, 0);
  }

  const int fr = lane & 15;
  const int rq = lane >> 4;
  unsigned short* Cb = (unsigned short*)Cv + z * zC;
  float* Cf = (float*)Cv + z * zC;
#pragma unroll
  for (int i = 0; i < 4; ++i) {
    const int rbase = m0 + wm * 64 + i * 16 + rq * 4;
#pragma unroll
    for (int j = 0; j < NT; ++j) {
      const int col = n0 + wn * WN + j * 16 + fr;
      const float bvv = biasz ? biasz[col] : 0.f;
#pragma unroll
      for (int r = 0; r < 4; ++r) {
        float v = acc[i][j][r] + bvv;
        if (ADD_RES) v += res[(size_t)(rbase + r) * ldres + col];
        if (RELU) v = fmaxf(v, 0.f);
        if (OUT_BF16) Cb[(size_t)(rbase + r) * ldc + col] = f32_to_bf16_bits(v);
        else Cf[(size_t)(rbase + r) * ldc + col] = v;
      }
    }
  }
}

// ---------------- fused scores/softmax/vbar (in-place U -> vbar), v3 ----------------
// 8 tokens per block; k/v staged fp32 into double-buffered LDS via
// global_load_lds DMA (zero VGPR prefetch cost, no packing VALU).
// s[h,c] = U[n,h,:] . key[n*8+c,:] / 8; softmax over c;
// vbar[n,h,:] = sum_c att[c] * value[n*8+c,:]  (written over U, bf16)
// Lane j-mapping: lane covers j = lane*4 + t*256, t in {0,1}  (all LDS reads b128).
__global__ __launch_bounds__(256) void attn_kernel(const float* __restrict__ key,
                                                   const float* __restrict__ value,
                                                   unsigned short* __restrict__ U) {
  extern __shared__ float smem[];  // 2 buffers x (k 4096 floats + v 4096 floats) = 64 KB
  const int tid = (int)threadIdx.x;
  const int lane = tid & 63;
  const int w = tid >> 6;
  const int n0 = (int)blockIdx.x * 8;

  // DMA one token's k+v (32 KB fp32) into buffer `buf`. Wave w covers floats
  // [w*1024, w*1024+1024) of each of k and v, in 4 issues of 1 KB.
  auto issue = [&](int n, int buf) {
    const float* kg = key + (size_t)n * 4096;
    const float* vg = value + (size_t)n * 4096;
    float* kl = smem + buf * 8192;
    float* vl = kl + 4096;
#pragma unroll
    for (int j = 0; j < 4; ++j) {
      const int o = w * 1024 + j * 256;  // wave-uniform float offset
      load_lds16(kg + o + lane * 4, kl + o);
      load_lds16(vg + o + lane * 4, vl + o);
    }
  };

  issue(n0, 0);

  for (int i = 0; i < 8; ++i) {
    asm volatile("s_waitcnt vmcnt(0)" ::: "memory");  // own DMA landed
    __syncthreads();                                   // all waves' DMA landed; prev buffer free
    if (i < 7) issue(n0 + i + 1, (i + 1) & 1);

    const float* kf = smem + (i & 1) * 8192;
    const float* vf = kf + 4096;
    uint32_t* Un32 = (uint32_t*)(U + (size_t)(n0 + i) * 4096);

#pragma unroll
    for (int hh = 0; hh < 2; ++hh) {
      const int h = w * 2 + hh;
      // u: 8 bf16 of U[n,h,:] at j = lane*4 + t*256  ->  dword pairs
      uint2 ud0 = *(const uint2*)(Un32 + h * 256 + lane * 2);
      uint2 ud1 = *(const uint2*)(Un32 + h * 256 + 128 + lane * 2);
      float u[8] = {bf16_lo(ud0.x), bf16_hi(ud0.x), bf16_lo(ud0.y), bf16_hi(ud0.y),
                    bf16_lo(ud1.x), bf16_hi(ud1.x), bf16_lo(ud1.y), bf16_hi(ud1.y)};

      float zc[8];
      float zmax = -1e30f;
#pragma unroll
      for (int c = 0; c < 8; ++c) {
        float4 k0 = *(const float4*)(kf + c * 512 + lane * 4);
        float4 k1 = *(const float4*)(kf + c * 512 + 256 + lane * 4);
        float p = u[0] * k0.x + u[1] * k0.y + u[2] * k0.z + u[3] * k0.w +
                  u[4] * k1.x + u[5] * k1.y + u[6] * k1.z + u[7] * k1.w;
#pragma unroll
        for (int off = 32; off > 0; off >>= 1) p += __shfl_xor(p, off, 64);
        zc[c] = p * 0.125f;  // / sqrt(64)
        zmax = fmaxf(zmax, zc[c]);
      }
      float se = 0.f;
#pragma unroll
      for (int c = 0; c < 8; ++c) { zc[c] = __expf(zc[c] - zmax); se += zc[c]; }
      const float inv = 1.f / se;
#pragma unroll
      for (int c = 0; c < 8; ++c) zc[c] *= inv;

      float a[8] = {0.f, 0.f, 0.f, 0.f, 0.f, 0.f, 0.f, 0.f};
#pragma unroll
      for (int c = 0; c < 8; ++c) {
        float4 v0 = *(const float4*)(vf + c * 512 + lane * 4);
        float4 v1 = *(const float4*)(vf + c * 512 + 256 + lane * 4);
        a[0] += zc[c] * v0.x; a[1] += zc[c] * v0.y;
        a[2] += zc[c] * v0.z; a[3] += zc[c] * v0.w;
        a[4] += zc[c] * v1.x; a[5] += zc[c] * v1.y;
        a[6] += zc[c] * v1.z; a[7] += zc[c] * v1.w;
      }
      uint2 s0, s1;
      s0.x = pack_bf16x2(a[0], a[1]); s0.y = pack_bf16x2(a[2], a[3]);
      s1.x = pack_bf16x2(a[4], a[5]); s1.y = pack_bf16x2(a[6], a[7]);
      *(uint2*)(Un32 + h * 256 + lane * 2) = s0;
      *(uint2*)(Un32 + h * 256 + 128 + lane * 2) = s1;
    }
    // no trailing barrier: next iteration's waitcnt+barrier orders LDS reads
    // of this buffer before the DMA that overwrites it.
  }
}

// ---------------- LayerNorm over rows of 512; wave per row ----------------
__global__ __launch_bounds__(256) void ln_kernel(const float* __restrict__ in,
                                                 const float* __restrict__ g,
                                                 const float* __restrict__ b,
                                                 float* __restrict__ outf,
                                                 unsigned short* __restrict__ outb) {
  const int lane = (int)threadIdx.x & 63;
  const size_t row = (size_t)blockIdx.x * 4 + (threadIdx.x >> 6);
  const int col = lane * 8;
  const float* x = in + row * 512;
  float4 a0 = *(const float4*)(x + col);
  float4 a1 = *(const float4*)(x + col + 4);
  float v[8] = {a0.x, a0.y, a0.z, a0.w, a1.x, a1.y, a1.z, a1.w};
  float s = 0.f, sq = 0.f;
#pragma unroll
  for (int t = 0; t < 8; ++t) { s += v[t]; sq += v[t] * v[t]; }
#pragma unroll
  for (int off = 32; off > 0; off >>= 1) {
    s += __shfl_xor(s, off, 64);
    sq += __shfl_xor(sq, off, 64);
  }
  const float mean = s * (1.f / 512.f);
  const float var = sq * (1.f / 512.f) - mean * mean;
  const float rstd = rsqrtf(var + 1e-5f);
  float o[8];
#pragma unroll
  for (int t = 0; t < 8; ++t) o[t] = (v[t] - mean) * rstd * g[col + t] + b[col + t];
  if (outf) {
    *(float4*)(outf + row * 512 + col) = make_float4(o[0], o[1], o[2], o[3]);
    *(float4*)(outf + row * 512 + col + 4) = make_float4(o[4], o[5], o[6], o[7]);
  }
  if (outb) {
    union { unsigned short s_[8]; uint4 v_; } u;
#pragma unroll
    for (int t = 0; t < 8; ++t) u.s_[t] = f32_to_bf16_bits(o[t]);
    *(uint4*)(outb + row * 512 + col) = u.v_;
  }
}

extern "C" void kernel_launch(void* const* d_in, const int* in_sizes, int n_in,
                              void* d_out, int out_size, void* d_ws, size_t ws_size,
                              hipStream_t stream) {
  const float* query = (const float*)d_in[0];
  const float* key   = (const float*)d_in[1];
  const float* value = (const float*)d_in[2];
  const float* Wq = (const float*)d_in[3];
  const float* bq = (const float*)d_in[4];
  const float* Wk = (const float*)d_in[5];
  // bk (d_in[6]) cancels exactly in the softmax -> unused
  const float* Wv = (const float*)d_in[7];
  const float* bv = (const float*)d_in[8];
  const float* Wo = (const float*)d_in[9];
  const float* bo = (const float*)d_in[10];
  const float* ln1g = (const float*)d_in[11];
  const float* ln1b = (const float*)d_in[12];
  const float* W1 = (const float*)d_in[13];
  const float* b1 = (const float*)d_in[14];
  const float* W2 = (const float*)d_in[15];
  const float* b2 = (const float*)d_in[16];
  const float* ln2g = (const float*)d_in[17];
  const float* ln2b = (const float*)d_in[18];
  float* out = (float*)d_out;

  char* ws = (char*)d_ws;
  size_t off = 0;
  auto alloc = [&](size_t bytes) -> void* {
    off = (off + 255) & ~(size_t)255;
    void* p = ws + off;
    off += bytes;
    return p;
  };

  const int N = 8192;  // tokens = F*B
  unsigned short* qb   = (unsigned short*)alloc((size_t)N * 512 * 2);
  unsigned short* Wqb  = (unsigned short*)alloc(512 * 512 * 2);
  unsigned short* Wvb  = (unsigned short*)alloc(512 * 512 * 2);
  unsigned short* Wob  = (unsigned short*)alloc(512 * 512 * 2);
  unsigned short* W1b  = (unsigned short*)alloc(1024 * 512 * 2);
  unsigned short* W2b  = (unsigned short*)alloc(512 * 1024 * 2);
  unsigned short* WkT  = (unsigned short*)alloc(8 * 512 * 64 * 2);
  unsigned short* Qp   = (unsigned short*)alloc((size_t)N * 512 * 2);   // later reused as x
  unsigned short* U    = (unsigned short*)alloc((size_t)N * 4096 * 2);  // U, then vbar in-place
  float*          h1pre= (float*)alloc((size_t)N * 512 * 4);            // later reused as o2pre
  unsigned short* h1b  = (unsigned short*)alloc((size_t)N * 512 * 2);
  float*          h1f  = (float*)alloc((size_t)N * 512 * 4);
  unsigned short* mid  = (unsigned short*)alloc((size_t)N * 1024 * 2);
  unsigned short* x    = Qp;       // reuse (Qp dead after U-GEMM)
  float*          o2pre= h1pre;    // reuse (raw pre-LN1 dead after LN1)
  (void)ws_size; (void)in_sizes; (void)n_in; (void)out_size;

  dim3 blk(256);
  // all straight conversions in one launch; WkT transpose separately
  cvt_all<<<2944, blk, 0, stream>>>(query, Wq, Wv, Wo, W1, W2,
                                    qb, Wqb, Wvb, Wob, W1b, W2b);
  wkt_kernel<<<1024, blk, 0, stream>>>(Wk, WkT);

  // Qp = qb @ Wq^T + bq            [8192 x 512], bf16
  gemm_bt<128, true, false, false><<<dim3(4, 64, 1), blk, 0, stream>>>(
      qb, 512, 0, Wqb, 512, 0, Qp, 512, 0, bq, 0, nullptr, 0, 512);
  // U[n, h*512+j] = Qp[n, h*64:..] @ WkT[h]   (K=64 per head, grid.z = head)
  gemm_bt<128, true, false, false><<<dim3(4, 64, 8), blk, 0, stream>>>(
      Qp, 512, 64, WkT, 64, 32768, U, 4096, 512, nullptr, 0, nullptr, 0, 64);
  // scores + softmax + vbar (in place over U); 8 tokens/block, DMA double-buffer
  attn_kernel<<<1024, blk, 65536, stream>>>(key, value, U);
  // x[n, h*64+d] = vbar[n,h,:] @ Wv_head^T + bv_head   (N=64 per head)
  gemm_bt<64, true, false, false><<<dim3(1, 64, 8), blk, 0, stream>>>(
      U, 4096, 512, Wvb, 512, 32768, x, 512, 64, bv, 64, nullptr, 0, 512);
  // h1pre = x @ Wo^T + bo + query   (fp32)
  gemm_bt<128, false, false, true><<<dim3(4, 64, 1), blk, 0, stream>>>(
      x, 512, 0, Wob, 512, 0, h1pre, 512, 0, bo, 0, query, 512, 512);
  // h1 = LN(h1pre) -> h1f (fp32 residual) + h1b (bf16 GEMM input)
  ln_kernel<<<2048, blk, 0, stream>>>(h1pre, ln1g, ln1b, h1f, h1b);
  // mid = relu(h1 @ W1^T + b1)      [8192 x 1024], bf16
  gemm_bt<128, true, true, false><<<dim3(8, 64, 1), blk, 0, stream>>>(
      h1b, 512, 0, W1b, 512, 0, mid, 1024, 0, b1, 0, nullptr, 0, 512);
  // o2pre = mid @ W2^T + b2 + h1    (fp32)
  gemm_bt<128, false, false, true><<<dim3(4, 64, 1), blk, 0, stream>>>(
      mid, 1024, 0, W2b, 1024, 0, o2pre, 512, 0, b2, 0, h1f, 512, 1024);
  // out = LN(o2pre)
  ln_kernel<<<2048, blk, 0, stream>>>(o2pre, ln2g, ln2b, out, nullptr);
}

// Round 4
// 505.019 us; speedup vs baseline: 1.4106x; 1.1092x over previous
//
#include <hip/hip_runtime.h>
#include <cstdint>
#include <cstddef>

#define DEVFN static __device__ __forceinline__

typedef __attribute__((ext_vector_type(4))) float f32x4;
typedef __attribute__((ext_vector_type(8))) __bf16 bf16x8;

typedef __attribute__((address_space(1))) void gvoid;
typedef __attribute__((address_space(3))) void svoid;

DEVFN unsigned short f32_to_bf16_bits(float f) {
  uint32_t u = __builtin_bit_cast(uint32_t, f);
  return (unsigned short)((u + 0x7fffu + ((u >> 16) & 1u)) >> 16);
}
DEVFN float bf16_lo(uint32_t d) { return __builtin_bit_cast(float, d << 16); }
DEVFN float bf16_hi(uint32_t d) { return __builtin_bit_cast(float, d & 0xffff0000u); }
DEVFN uint32_t pack_bf16x2(float lo, float hi) {
  return (uint32_t)f32_to_bf16_bits(lo) | ((uint32_t)f32_to_bf16_bits(hi) << 16);
}

// global -> LDS direct copy, 16B per lane. LDS base must be wave-uniform;
// lane i lands at lds + i*16 bytes.
DEVFN void load_lds16(const void* g, void* l) {
  __builtin_amdgcn_global_load_lds((const gvoid*)g, (svoid*)l, 16, 0, 0);
}

// ---------------- all fp32 -> bf16 conversions + WkT transpose, ONE launch ----------------
// chunk = 8 output elems. Ranges (block-aligned):
//   [0,524288)        query -> qb
//   [524288,557056)   Wq -> Wqb
//   [557056,589824)   Wv -> Wvb
//   [589824,622592)   Wo -> Wob
//   [622592,688128)   W1 -> W1b
//   [688128,753664)   W2 -> W2b
//   [753664,786432)   Wk -> WkT[h][j][d] transpose
__global__ __launch_bounds__(256) void cvt_all(
    const float* __restrict__ q, const float* __restrict__ Wq,
    const float* __restrict__ Wv, const float* __restrict__ Wo,
    const float* __restrict__ W1, const float* __restrict__ W2,
    const float* __restrict__ Wk,
    unsigned short* __restrict__ qb, unsigned short* __restrict__ Wqb,
    unsigned short* __restrict__ Wvb, unsigned short* __restrict__ Wob,
    unsigned short* __restrict__ W1b, unsigned short* __restrict__ W2b,
    unsigned short* __restrict__ WkT) {
  int i = (int)(blockIdx.x * 256 + threadIdx.x);
  if (i >= 753664) {  // WkT transpose tail (wave-uniform branch; ranges block-aligned)
    int off = i - 753664;
    int oidx = off * 8;
    int d0 = oidx & 63;
    int j = (oidx >> 6) & 511;
    int h = oidx >> 15;
    union { unsigned short s[8]; uint4 v; } o;
#pragma unroll
    for (int t = 0; t < 8; ++t)
      o.s[t] = f32_to_bf16_bits(Wk[(size_t)((h << 6) + d0 + t) * 512 + j]);
    ((uint4*)WkT)[off] = o.v;
    return;
  }
  const float* src;
  unsigned short* dst;
  int off;
  if (i < 524288)      { src = q;  dst = qb;  off = i; }
  else if (i < 557056) { src = Wq; dst = Wqb; off = i - 524288; }
  else if (i < 589824) { src = Wv; dst = Wvb; off = i - 557056; }
  else if (i < 622592) { src = Wo; dst = Wob; off = i - 589824; }
  else if (i < 688128) { src = W1; dst = W1b; off = i - 622592; }
  else                 { src = W2; dst = W2b; off = i - 688128; }
  const float4* p = (const float4*)src;
  float4 a = p[2 * off], b = p[2 * off + 1];
  union { unsigned short s[8]; uint4 v; } o;
  o.s[0] = f32_to_bf16_bits(a.x); o.s[1] = f32_to_bf16_bits(a.y);
  o.s[2] = f32_to_bf16_bits(a.z); o.s[3] = f32_to_bf16_bits(a.w);
  o.s[4] = f32_to_bf16_bits(b.x); o.s[5] = f32_to_bf16_bits(b.y);
  o.s[6] = f32_to_bf16_bits(b.z); o.s[7] = f32_to_bf16_bits(b.w);
  ((uint4*)dst)[off] = o.v;
}

// ---------------- bf16 MFMA GEMM, B given transposed (Bt[n][k]) ----------------
// C[m][n] = sum_k A[m][k]*Bt[n][k] (+bias[n]) (+res[m][n]) (relu) -> bf16|f32
// 4 waves in 2x2; wave tile (BM/2) x (BN/2); BK=32.
template<int BM, int BN, bool OUT_BF16, bool RELU, bool ADD_RES>
__global__ __launch_bounds__(256)
void gemm_bt(const unsigned short* __restrict__ A, int lda, long long zA,
             const unsigned short* __restrict__ Bt, int ldb, long long zB,
             void* __restrict__ Cv, int ldc, long long zC,
             const float* __restrict__ bias, int zBias,
             const float* __restrict__ res, int ldres,
             int K) {
  constexpr int MT = BM / 32;  // mfma row-tiles per wave
  constexpr int NT = BN / 32;  // mfma col-tiles per wave
  constexpr int AQ = BM / 64;  // A staging issues per wave (1KB each)
  constexpr int BQ = BN / 64;
  __shared__ __align__(16) unsigned short As[BM * 32];
  __shared__ __align__(16) unsigned short Bs[BN * 32];

  const int tid = (int)threadIdx.x;
  const int lane = tid & 63;
  const int w = tid >> 6;
  const int wm = w >> 1;
  const int wn = w & 1;
  const int m0 = (int)blockIdx.y * BM;
  const int n0 = (int)blockIdx.x * BN;
  const long long z = (long long)blockIdx.z;

  A += z * zA;
  Bt += z * zB;
  const float* biasz = bias ? (bias + z * zBias) : nullptr;

  f32x4 acc[MT][NT];
#pragma unroll
  for (int i = 0; i < MT; ++i)
#pragma unroll
    for (int j = 0; j < NT; ++j) acc[i][j] = f32x4{0.f, 0.f, 0.f, 0.f};

  // staging: issue q covers bytes [q*4096 + w*1024, +1024); row = o/64, kcol = (o&63)/2
  int rA[AQ], cA[AQ], rB[BQ], cB[BQ];
#pragma unroll
  for (int q = 0; q < AQ; ++q) {
    const int o = q * 4096 + w * 1024 + lane * 16;
    rA[q] = o >> 6; cA[q] = (o & 63) >> 1;
  }
#pragma unroll
  for (int q = 0; q < BQ; ++q) {
    const int o = q * 4096 + w * 1024 + lane * 16;
    rB[q] = o >> 6; cB[q] = (o & 63) >> 1;
  }

  const int kIters = K / 32;
  for (int kt = 0; kt < kIters; ++kt) {
    const int k0 = kt * 32;
    __syncthreads();
#pragma unroll
    for (int q = 0; q < AQ; ++q)
      load_lds16(A + (size_t)(m0 + rA[q]) * lda + (k0 + cA[q]), As + q * 2048 + w * 512);
#pragma unroll
    for (int q = 0; q < BQ; ++q)
      load_lds16(Bt + (size_t)(n0 + rB[q]) * ldb + (k0 + cB[q]), Bs + q * 2048 + w * 512);
    asm volatile("s_waitcnt vmcnt(0)" ::: "memory");
    __syncthreads();

    const int fr = lane & 15;
    const int kq = lane >> 4;
    bf16x8 af[MT], bf[NT];
#pragma unroll
    for (int i = 0; i < MT; ++i) {
      const int m = wm * (BM / 2) + i * 16 + fr;
      af[i] = __builtin_bit_cast(bf16x8, *(const uint4*)(As + m * 32 + kq * 8));
    }
#pragma unroll
    for (int j = 0; j < NT; ++j) {
      const int n = wn * (BN / 2) + j * 16 + fr;
      bf[j] = __builtin_bit_cast(bf16x8, *(const uint4*)(Bs + n * 32 + kq * 8));
    }
#pragma unroll
    for (int i = 0; i < MT; ++i)
#pragma unroll
      for (int j = 0; j < NT; ++j)
        acc[i][j] = __builtin_amdgcn_mfma_f32_16x16x32_bf16(af[i], bf[j], acc[i][j], 0, 0, 0);
  }

  // epilogue: C/D layout col=lane&15, row=(lane>>4)*4+reg
  const int fr = lane & 15;
  const int rq = lane >> 4;
  unsigned short* Cb = (unsigned short*)Cv + z * zC;
  float* Cf = (float*)Cv + z * zC;
#pragma unroll
  for (int i = 0; i < MT; ++i) {
    const int rbase = m0 + wm * (BM / 2) + i * 16 + rq * 4;
#pragma unroll
    for (int j = 0; j < NT; ++j) {
      const int col = n0 + wn * (BN / 2) + j * 16 + fr;
      const float bvv = biasz ? biasz[col] : 0.f;
#pragma unroll
      for (int r = 0; r < 4; ++r) {
        float v = acc[i][j][r] + bvv;
        if (ADD_RES) v += res[(size_t)(rbase + r) * ldres + col];
        if (RELU) v = fmaxf(v, 0.f);
        if (OUT_BF16) Cb[(size_t)(rbase + r) * ldc + col] = f32_to_bf16_bits(v);
        else Cf[(size_t)(rbase + r) * ldc + col] = v;
      }
    }
  }
}

// ---------------- fused scores/softmax/vbar (in-place U -> vbar), v4 ----------------
// Register-resident, wave-per-token, NO LDS, no barriers.
// Lane l owns j-slice [8l, 8l+8). k/v rows read straight from global (coalesced,
// each element exactly once). Scores via 64-lane shfl_xor butterflies.
// s[h,c] = U[n,h,:].key[n*8+c,:] / 8; softmax over c;
// vbar[n,h,:] = sum_c att[c]*value[n*8+c,:]  (written over U, bf16)
__global__ __launch_bounds__(256) void attn_kernel(const float* __restrict__ key,
                                                   const float* __restrict__ value,
                                                   unsigned short* __restrict__ U) {
  const int lane = (int)threadIdx.x & 63;
  const int n = (int)blockIdx.x * 4 + ((int)threadIdx.x >> 6);

  // load + unpack u[h][t]: token row = 512 uint4; head h = 64 uint4; lane -> one uint4
  const uint4* Uq = (const uint4*)(U + (size_t)n * 4096);
  float u[8][8];
#pragma unroll
  for (int h = 0; h < 8; ++h) {
    uint4 d = Uq[h * 64 + lane];
    u[h][0] = bf16_lo(d.x); u[h][1] = bf16_hi(d.x);
    u[h][2] = bf16_lo(d.y); u[h][3] = bf16_hi(d.y);
    u[h][4] = bf16_lo(d.z); u[h][5] = bf16_hi(d.z);
    u[h][6] = bf16_lo(d.w); u[h][7] = bf16_hi(d.w);
  }

  // phase 1: scores zc[h][c]
  float zc[8][8];
#pragma unroll
  for (int c = 0; c < 8; ++c) {
    const float4* kp = (const float4*)(key + ((size_t)n * 8 + c) * 512);
    float4 k0 = kp[lane * 2];
    float4 k1 = kp[lane * 2 + 1];
    float p[8];
#pragma unroll
    for (int h = 0; h < 8; ++h) {
      p[h] = u[h][0] * k0.x + u[h][1] * k0.y + u[h][2] * k0.z + u[h][3] * k0.w +
             u[h][4] * k1.x + u[h][5] * k1.y + u[h][6] * k1.z + u[h][7] * k1.w;
    }
#pragma unroll
    for (int off = 1; off < 64; off <<= 1) {
#pragma unroll
      for (int h = 0; h < 8; ++h) p[h] += __shfl_xor(p[h], off, 64);
    }
#pragma unroll
    for (int h = 0; h < 8; ++h) zc[h][c] = p[h] * 0.125f;  // /sqrt(64)
  }

  // softmax over c, per head (every lane holds identical copies)
#pragma unroll
  for (int h = 0; h < 8; ++h) {
    float m = zc[h][0];
#pragma unroll
    for (int c = 1; c < 8; ++c) m = fmaxf(m, zc[h][c]);
    float se = 0.f;
#pragma unroll
    for (int c = 0; c < 8; ++c) { zc[h][c] = __expf(zc[h][c] - m); se += zc[h][c]; }
    const float inv = 1.f / se;
#pragma unroll
    for (int c = 0; c < 8; ++c) zc[h][c] *= inv;
  }

  // phase 2: vbar accumulate over c
  float acc[8][8];
#pragma unroll
  for (int h = 0; h < 8; ++h)
#pragma unroll
    for (int t = 0; t < 8; ++t) acc[h][t] = 0.f;
#pragma unroll
  for (int c = 0; c < 8; ++c) {
    const float4* vp = (const float4*)(value + ((size_t)n * 8 + c) * 512);
    float4 v0 = vp[lane * 2];
    float4 v1 = vp[lane * 2 + 1];
#pragma unroll
    for (int h = 0; h < 8; ++h) {
      const float a = zc[h][c];
      acc[h][0] += a * v0.x; acc[h][1] += a * v0.y;
      acc[h][2] += a * v0.z; acc[h][3] += a * v0.w;
      acc[h][4] += a * v1.x; acc[h][5] += a * v1.y;
      acc[h][6] += a * v1.z; acc[h][7] += a * v1.w;
    }
  }

  // write vbar over U (bf16)
  uint4* Uw = (uint4*)(U + (size_t)n * 4096);
#pragma unroll
  for (int h = 0; h < 8; ++h) {
    uint4 o;
    o.x = pack_bf16x2(acc[h][0], acc[h][1]);
    o.y = pack_bf16x2(acc[h][2], acc[h][3]);
    o.z = pack_bf16x2(acc[h][4], acc[h][5]);
    o.w = pack_bf16x2(acc[h][6], acc[h][7]);
    Uw[h * 64 + lane] = o;
  }
}

// ---------------- LayerNorm over rows of 512; wave per row ----------------
__global__ __launch_bounds__(256) void ln_kernel(const float* __restrict__ in,
                                                 const float* __restrict__ g,
                                                 const float* __restrict__ b,
                                                 float* __restrict__ outf,
                                                 unsigned short* __restrict__ outb) {
  const int lane = (int)threadIdx.x & 63;
  const size_t row = (size_t)blockIdx.x * 4 + (threadIdx.x >> 6);
  const int col = lane * 8;
  const float* x = in + row * 512;
  float4 a0 = *(const float4*)(x + col);
  float4 a1 = *(const float4*)(x + col + 4);
  float v[8] = {a0.x, a0.y, a0.z, a0.w, a1.x, a1.y, a1.z, a1.w};
  float s = 0.f, sq = 0.f;
#pragma unroll
  for (int t = 0; t < 8; ++t) { s += v[t]; sq += v[t] * v[t]; }
#pragma unroll
  for (int off = 32; off > 0; off >>= 1) {
    s += __shfl_xor(s, off, 64);
    sq += __shfl_xor(sq, off, 64);
  }
  const float mean = s * (1.f / 512.f);
  const float var = sq * (1.f / 512.f) - mean * mean;
  const float rstd = rsqrtf(var + 1e-5f);
  float o[8];
#pragma unroll
  for (int t = 0; t < 8; ++t) o[t] = (v[t] - mean) * rstd * g[col + t] + b[col + t];
  if (outf) {
    *(float4*)(outf + row * 512 + col) = make_float4(o[0], o[1], o[2], o[3]);
    *(float4*)(outf + row * 512 + col + 4) = make_float4(o[4], o[5], o[6], o[7]);
  }
  if (outb) {
    union { unsigned short s_[8]; uint4 v_; } u;
#pragma unroll
    for (int t = 0; t < 8; ++t) u.s_[t] = f32_to_bf16_bits(o[t]);
    *(uint4*)(outb + row * 512 + col) = u.v_;
  }
}

extern "C" void kernel_launch(void* const* d_in, const int* in_sizes, int n_in,
                              void* d_out, int out_size, void* d_ws, size_t ws_size,
                              hipStream_t stream) {
  const float* query = (const float*)d_in[0];
  const float* key   = (const float*)d_in[1];
  const float* value = (const float*)d_in[2];
  const float* Wq = (const float*)d_in[3];
  const float* bq = (const float*)d_in[4];
  const float* Wk = (const float*)d_in[5];
  // bk (d_in[6]) cancels exactly in the softmax -> unused
  const float* Wv = (const float*)d_in[7];
  const float* bv = (const float*)d_in[8];
  const float* Wo = (const float*)d_in[9];
  const float* bo = (const float*)d_in[10];
  const float* ln1g = (const float*)d_in[11];
  const float* ln1b = (const float*)d_in[12];
  const float* W1 = (const float*)d_in[13];
  const float* b1 = (const float*)d_in[14];
  const float* W2 = (const float*)d_in[15];
  const float* b2 = (const float*)d_in[16];
  const float* ln2g = (const float*)d_in[17];
  const float* ln2b = (const float*)d_in[18];
  float* out = (float*)d_out;

  char* ws = (char*)d_ws;
  size_t off = 0;
  auto alloc = [&](size_t bytes) -> void* {
    off = (off + 255) & ~(size_t)255;
    void* p = ws + off;
    off += bytes;
    return p;
  };

  const int N = 8192;  // tokens = F*B
  unsigned short* qb   = (unsigned short*)alloc((size_t)N * 512 * 2);
  unsigned short* Wqb  = (unsigned short*)alloc(512 * 512 * 2);
  unsigned short* Wvb  = (unsigned short*)alloc(512 * 512 * 2);
  unsigned short* Wob  = (unsigned short*)alloc(512 * 512 * 2);
  unsigned short* W1b  = (unsigned short*)alloc(1024 * 512 * 2);
  unsigned short* W2b  = (unsigned short*)alloc(512 * 1024 * 2);
  unsigned short* WkT  = (unsigned short*)alloc(8 * 512 * 64 * 2);
  unsigned short* Qp   = (unsigned short*)alloc((size_t)N * 512 * 2);   // later reused as x
  unsigned short* U    = (unsigned short*)alloc((size_t)N * 4096 * 2);  // U, then vbar in-place
  float*          h1pre= (float*)alloc((size_t)N * 512 * 4);            // later reused as o2pre
  unsigned short* h1b  = (unsigned short*)alloc((size_t)N * 512 * 2);
  float*          h1f  = (float*)alloc((size_t)N * 512 * 4);
  unsigned short* mid  = (unsigned short*)alloc((size_t)N * 1024 * 2);
  unsigned short* x    = Qp;       // reuse (Qp dead after U-GEMM)
  float*          o2pre= h1pre;    // reuse (raw pre-LN1 dead after LN1)
  (void)ws_size; (void)in_sizes; (void)n_in; (void)out_size;

  dim3 blk(256);
  // all conversions + WkT transpose in one launch
  cvt_all<<<3072, blk, 0, stream>>>(query, Wq, Wv, Wo, W1, W2, Wk,
                                    qb, Wqb, Wvb, Wob, W1b, W2b, WkT);

  // Qp = qb @ Wq^T + bq            [8192 x 512], bf16   (64x64 tiles, 1024 blocks)
  gemm_bt<64, 64, true, false, false><<<dim3(8, 128, 1), blk, 0, stream>>>(
      qb, 512, 0, Wqb, 512, 0, Qp, 512, 0, bq, 0, nullptr, 0, 512);
  // U[n, h*512+j] = Qp[n, h*64:..] @ WkT[h]   (K=64 per head, grid.z = head; 2048 blocks)
  gemm_bt<128, 128, true, false, false><<<dim3(4, 64, 8), blk, 0, stream>>>(
      Qp, 512, 64, WkT, 64, 32768, U, 4096, 512, nullptr, 0, nullptr, 0, 64);
  // scores + softmax + vbar, register-resident wave-per-token (2048 blocks)
  attn_kernel<<<2048, blk, 0, stream>>>(key, value, U);
  // x[n, h*64+d] = vbar[n,h,:] @ Wv_head^T + bv_head   (N=64 per head; 1024 blocks)
  gemm_bt<64, 64, true, false, false><<<dim3(1, 128, 8), blk, 0, stream>>>(
      U, 4096, 512, Wvb, 512, 32768, x, 512, 64, bv, 64, nullptr, 0, 512);
  // h1pre = x @ Wo^T + bo + query   (fp32; 1024 blocks)
  gemm_bt<64, 64, false, false, true><<<dim3(8, 128, 1), blk, 0, stream>>>(
      x, 512, 0, Wob, 512, 0, h1pre, 512, 0, bo, 0, query, 512, 512);
  // h1 = LN(h1pre) -> h1f (fp32 residual) + h1b (bf16 GEMM input)
  ln_kernel<<<2048, blk, 0, stream>>>(h1pre, ln1g, ln1b, h1f, h1b);
  // mid = relu(h1 @ W1^T + b1)      [8192 x 1024], bf16  (2048 blocks)
  gemm_bt<64, 64, true, true, false><<<dim3(16, 128, 1), blk, 0, stream>>>(
      h1b, 512, 0, W1b, 512, 0, mid, 1024, 0, b1, 0, nullptr, 0, 512);
  // o2pre = mid @ W2^T + b2 + h1    (fp32; 1024 blocks)
  gemm_bt<64, 64, false, false, true><<<dim3(8, 128, 1), blk, 0, stream>>>(
      mid, 1024, 0, W2b, 1024, 0, o2pre, 512, 0, b2, 0, h1f, 512, 1024);
  // out = LN(o2pre)
  ln_kernel<<<2048, blk, 0, stream>>>(o2pre, ln2g, ln2b, out, nullptr);
}